// Round 5
// baseline (123.635 us; speedup 1.0000x reference)
//
#include <hip/hip_runtime.h>

typedef float f32x4 __attribute__((ext_vector_type(4)));

// ---------------------------------------------------------------------------
// Fully fused: each block (a) computes the exact k-th-largest threshold of
// kernel[] via bitwise binary search on order-preserving uint keys (~5
// iterations, ~3 us, overlapped across all co-resident blocks — replaces the
// separate dispatch + launch gap), then (b) streams out = x * sel where each
// thread's two FIXED columns' sel values are derived once, in registers.
// Streaming uses contiguous PAIRS of float4 (32 B/lane) for 2 outstanding
// loads at adjacent addresses (no power-of-2 MB-scale stride between them).
// ---------------------------------------------------------------------------
__global__ void __launch_bounds__(256)
fused_select_mul(const f32x4* __restrict__ x,
                 const float* __restrict__ kern,
                 const int* __restrict__ kptr,
                 f32x4* __restrict__ out,
                 int D, int n4)
{
    const int tid  = threadIdx.x;
    const int lane = tid & 63;
    const int wid  = tid >> 6;

    __shared__ unsigned int s_umin[4], s_umax[4];
    __shared__ int s_cnt[4];

    // ---- Phase 1: exact k-th-largest threshold (per block, redundant) ----
    // order-preserving key: u = b ^ ((int(b)>>31) | 0x80000000)
    unsigned int u[16];
    #pragma unroll
    for (int j = 0; j < 16; ++j) {
        int i = tid + j * 256;
        if (i < D) {
            unsigned int b = __float_as_uint(kern[i]);
            u[j] = b ^ (unsigned int)(((int)b >> 31) | (int)0x80000000);
        } else {
            u[j] = 0u;  // pads sort below all real values
        }
    }

    unsigned int umin = 0xFFFFFFFFu, umax = 0u;
    #pragma unroll
    for (int j = 0; j < 16; ++j) {
        int i = tid + j * 256;
        if (i < D) { umin = min(umin, u[j]); umax = max(umax, u[j]); }
    }
    #pragma unroll
    for (int off = 32; off; off >>= 1) {
        umin = min(umin, (unsigned int)__shfl_down((int)umin, off, 64));
        umax = max(umax, (unsigned int)__shfl_down((int)umax, off, 64));
    }
    if (lane == 0) { s_umin[wid] = umin; s_umax[wid] = umax; }
    __syncthreads();
    umin = min(min(s_umin[0], s_umin[1]), min(s_umin[2], s_umin[3]));
    umax = max(max(s_umax[0], s_umax[1]), max(s_umax[2], s_umax[3]));

    const int kk = *kptr;
    unsigned int t;
    unsigned int xorv = umin ^ umax;
    if (xorv == 0u) {
        t = umax;
    } else {
        int hb = 31 - __builtin_clz(xorv);
        unsigned int lowmask = (hb == 31) ? 0xFFFFFFFFu : ((1u << (hb + 1)) - 1u);
        t = umax & ~lowmask;  // common prefix
        for (int bit = hb; bit >= 0; --bit) {
            unsigned int cand = t | (1u << bit);
            int c = 0;
            #pragma unroll
            for (int j = 0; j < 16; ++j) c += (u[j] >= cand) ? 1 : 0;
            #pragma unroll
            for (int off = 32; off; off >>= 1) c += __shfl_down(c, off, 64);
            __syncthreads();                 // protect s_cnt reuse
            if (lane == 0) s_cnt[wid] = c;
            __syncthreads();
            c = s_cnt[0] + s_cnt[1] + s_cnt[2] + s_cnt[3];
            if (c >= kk) t = cand;
        }
    }
    const float thr = __uint_as_float((t & 0x80000000u) ? (t ^ 0x80000000u) : ~t);

    // ---- Phase 2: streaming broadcast multiply over contiguous pairs ----
    const int gid    = blockIdx.x * 256 + tid;
    const int S      = gridDim.x * 256;        // pair stride
    const int d4mask = (D >> 2) - 1;
    const int n8     = n4 >> 1;                // number of float4 pairs
    const int prow   = D >> 3;                 // pairs per row
    const f32x4* kern4 = (const f32x4*)kern;

    if (prow > 0 && (S % prow) == 0) {
        // Each thread's pair of columns is fixed for all iterations.
        const int c0 = (2 * gid) & d4mask;     // even -> c1 = c0 + 1, no wrap
        f32x4 kv0 = kern4[c0];
        f32x4 kv1 = kern4[c0 + 1];
        f32x4 sv0, sv1;
        sv0.x = (kv0.x < thr) ? 0.0f : kv0.x;
        sv0.y = (kv0.y < thr) ? 0.0f : kv0.y;
        sv0.z = (kv0.z < thr) ? 0.0f : kv0.z;
        sv0.w = (kv0.w < thr) ? 0.0f : kv0.w;
        sv1.x = (kv1.x < thr) ? 0.0f : kv1.x;
        sv1.y = (kv1.y < thr) ? 0.0f : kv1.y;
        sv1.z = (kv1.z < thr) ? 0.0f : kv1.z;
        sv1.w = (kv1.w < thr) ? 0.0f : kv1.w;

        for (int p = gid; p < n8; p += S) {
            f32x4 a0 = __builtin_nontemporal_load(&x[2 * p]);
            f32x4 a1 = __builtin_nontemporal_load(&x[2 * p + 1]);
            __builtin_nontemporal_store(a0 * sv0, &out[2 * p]);
            __builtin_nontemporal_store(a1 * sv1, &out[2 * p + 1]);
        }
        // odd leftover float4 (n4 odd) — not taken for D=4096/B=16384
        if ((n4 & 1) && gid == 0) {
            int i = n4 - 1;
            f32x4 kv = kern4[i & d4mask];
            f32x4 sv;
            sv.x = (kv.x < thr) ? 0.0f : kv.x;
            sv.y = (kv.y < thr) ? 0.0f : kv.y;
            sv.z = (kv.z < thr) ? 0.0f : kv.z;
            sv.w = (kv.w < thr) ? 0.0f : kv.w;
            out[i] = x[i] * sv;
        }
    } else {
        // generic fallback: per-iteration sel
        for (int i = gid; i < n4; i += S) {
            f32x4 kv = kern4[i & d4mask];
            f32x4 sv;
            sv.x = (kv.x < thr) ? 0.0f : kv.x;
            sv.y = (kv.y < thr) ? 0.0f : kv.y;
            sv.z = (kv.z < thr) ? 0.0f : kv.z;
            sv.w = (kv.w < thr) ? 0.0f : kv.w;
            f32x4 a = __builtin_nontemporal_load(&x[i]);
            __builtin_nontemporal_store(a * sv, &out[i]);
        }
    }
}

extern "C" void kernel_launch(void* const* d_in, const int* in_sizes, int n_in,
                              void* d_out, int out_size, void* d_ws, size_t ws_size,
                              hipStream_t stream) {
    const float* x    = (const float*)d_in[0];
    const float* kern = (const float*)d_in[1];
    const int*   kptr = (const int*)d_in[2];
    float* out = (float*)d_out;

    const int D  = in_sizes[1];
    const int n4 = out_size / 4;   // B*D/4

    // 2048 blocks x 256 threads = exactly 8 blocks/CU co-resident.
    // Pair stride 524288 is a multiple of D/8=512 -> fixed-column fast path.
    fused_select_mul<<<2048, 256, 0, stream>>>(
        (const f32x4*)x, kern, kptr, (f32x4*)out, D, n4);
}

// Round 6
// 119.492 us; speedup vs baseline: 1.0347x; 1.0347x over previous
//
#include <hip/hip_runtime.h>

typedef float f32x4 __attribute__((ext_vector_type(4)));

// ---------------------------------------------------------------------------
// Kernel A: exact k-th-largest threshold via bitwise binary search on
// order-preserving uint transforms, then emit sel[d] = (kern[d]<thr)?0:kern[d].
// Single block, 256 threads, values in registers (16/thread for D=4096).
// Values span ~16 ULPs -> search runs ~5 iterations. ~3 us.
// ---------------------------------------------------------------------------
__global__ void __launch_bounds__(256)
select_threshold_kernel(const float* __restrict__ kern,
                        const int* __restrict__ kptr,
                        float* __restrict__ sel,
                        int D) {
    const int tid  = threadIdx.x;
    const int lane = tid & 63;
    const int wid  = tid >> 6;

    __shared__ unsigned int s_umin[4], s_umax[4];
    __shared__ int s_cnt[4];

    unsigned int u[16];
    #pragma unroll
    for (int j = 0; j < 16; ++j) {
        int i = tid + j * 256;
        if (i < D) {
            unsigned int b = __float_as_uint(kern[i]);
            u[j] = b ^ (unsigned int)(((int)b >> 31) | (int)0x80000000);
        } else {
            u[j] = 0u;
        }
    }

    unsigned int umin = 0xFFFFFFFFu, umax = 0u;
    #pragma unroll
    for (int j = 0; j < 16; ++j) {
        int i = tid + j * 256;
        if (i < D) { umin = min(umin, u[j]); umax = max(umax, u[j]); }
    }
    #pragma unroll
    for (int off = 32; off; off >>= 1) {
        umin = min(umin, (unsigned int)__shfl_down((int)umin, off, 64));
        umax = max(umax, (unsigned int)__shfl_down((int)umax, off, 64));
    }
    if (lane == 0) { s_umin[wid] = umin; s_umax[wid] = umax; }
    __syncthreads();
    umin = min(min(s_umin[0], s_umin[1]), min(s_umin[2], s_umin[3]));
    umax = max(max(s_umax[0], s_umax[1]), max(s_umax[2], s_umax[3]));

    const int kk = *kptr;
    unsigned int t;
    unsigned int xorv = umin ^ umax;
    if (xorv == 0u) {
        t = umax;
    } else {
        int hb = 31 - __builtin_clz(xorv);
        unsigned int lowmask = (hb == 31) ? 0xFFFFFFFFu : ((1u << (hb + 1)) - 1u);
        t = umax & ~lowmask;
        for (int bit = hb; bit >= 0; --bit) {
            unsigned int cand = t | (1u << bit);
            int c = 0;
            #pragma unroll
            for (int j = 0; j < 16; ++j) c += (u[j] >= cand) ? 1 : 0;
            #pragma unroll
            for (int off = 32; off; off >>= 1) c += __shfl_down(c, off, 64);
            __syncthreads();
            if (lane == 0) s_cnt[wid] = c;
            __syncthreads();
            c = s_cnt[0] + s_cnt[1] + s_cnt[2] + s_cnt[3];
            if (c >= kk) t = cand;
        }
    }

    float thr = __uint_as_float((t & 0x80000000u) ? (t ^ 0x80000000u) : ~t);

    #pragma unroll
    for (int j = 0; j < 16; ++j) {
        int i = tid + j * 256;
        if (i < D) {
            float v = kern[i];
            sel[i] = (v < thr) ? 0.0f : v;
        }
    }
}

// ---------------------------------------------------------------------------
// Kernel B: out[i] = x[i] * sel[i mod D/4] — the exact round-2 loop (best
// measured), with ONE change: plain loads/stores instead of nontemporal.
// NT bits bypass L2; harness fills sustain ~7 TB/s through L2 with plain
// stores, so let L2 write-combine for us.
// ---------------------------------------------------------------------------
__global__ void __launch_bounds__(256)
bcast_mul_kernel(const f32x4* __restrict__ x,
                 const f32x4* __restrict__ sel,
                 f32x4* __restrict__ out,
                 int n4, int d4mask) {
    int idx = blockIdx.x * blockDim.x + threadIdx.x;
    int stride = gridDim.x * blockDim.x;
    for (int i = idx; i < n4; i += stride) {
        f32x4 xv = x[i];
        f32x4 sv = sel[i & d4mask];
        f32x4 o = xv * sv;
        out[i] = o;
    }
}

extern "C" void kernel_launch(void* const* d_in, const int* in_sizes, int n_in,
                              void* d_out, int out_size, void* d_ws, size_t ws_size,
                              hipStream_t stream) {
    const float* x    = (const float*)d_in[0];
    const float* kern = (const float*)d_in[1];
    const int*   kptr = (const int*)d_in[2];
    float* out = (float*)d_out;
    float* sel = (float*)d_ws;  // D floats = 16 KiB scratch

    const int D = in_sizes[1];

    // Phase 1: exact threshold + selected kernel vector (single block, ~3 us)
    select_threshold_kernel<<<1, 256, 0, stream>>>(kern, kptr, sel, D);

    // Phase 2: streaming broadcast multiply (2048 blocks = 8/CU, 32 waves/CU)
    const int n4 = out_size / 4;          // B*D/4
    const int d4mask = (D / 4) - 1;       // D is a power of two (4096)
    bcast_mul_kernel<<<2048, 256, 0, stream>>>(
        (const f32x4*)x, (const f32x4*)sel, (f32x4*)out, n4, d4mask);
}

// Round 7
// 104.804 us; speedup vs baseline: 1.1797x; 1.1402x over previous
//
#include <hip/hip_runtime.h>

typedef float f32x4 __attribute__((ext_vector_type(4)));

// ---------------------------------------------------------------------------
// Kernel A: exact k-th-largest threshold via bitwise binary search on
// order-preserving uint transforms, then emit sel[d] = (kern[d]<thr)?0:kern[d].
// Single block, 256 threads, values held in registers (16/thread for D=4096).
// The kernel values span only ~16 ULPs, so after the min/max reduce the
// binary search runs ~4-5 iterations, each a cheap count+block-reduce.
// ---------------------------------------------------------------------------
__global__ void __launch_bounds__(256)
select_threshold_kernel(const float* __restrict__ kern,
                        const int* __restrict__ kptr,
                        float* __restrict__ sel,
                        int D) {
    const int tid  = threadIdx.x;
    const int lane = tid & 63;
    const int wid  = tid >> 6;

    __shared__ unsigned int s_umin[4], s_umax[4];
    __shared__ int s_cnt[4];

    // Load up to 16 values/thread into registers, as order-preserving uints:
    // for float f with bits b: u = b ^ ((int(b)>>31) | 0x80000000)
    // preserves total order (pos floats map above neg; uint compare == float compare).
    unsigned int u[16];
    #pragma unroll
    for (int j = 0; j < 16; ++j) {
        int i = tid + j * 256;
        if (i < D) {
            unsigned int b = __float_as_uint(kern[i]);
            u[j] = b ^ (unsigned int)(((int)b >> 31) | (int)0x80000000);
        } else {
            u[j] = 0u;  // pads sort below all real values
        }
    }

    // Block min/max reduce to find the common prefix (shrinks search to ~5 bits)
    unsigned int umin = 0xFFFFFFFFu, umax = 0u;
    #pragma unroll
    for (int j = 0; j < 16; ++j) {
        int i = tid + j * 256;
        if (i < D) { umin = min(umin, u[j]); umax = max(umax, u[j]); }
    }
    #pragma unroll
    for (int off = 32; off; off >>= 1) {
        umin = min(umin, (unsigned int)__shfl_down((int)umin, off, 64));
        umax = max(umax, (unsigned int)__shfl_down((int)umax, off, 64));
    }
    if (lane == 0) { s_umin[wid] = umin; s_umax[wid] = umax; }
    __syncthreads();
    umin = min(min(s_umin[0], s_umin[1]), min(s_umin[2], s_umin[3]));
    umax = max(max(s_umax[0], s_umax[1]), max(s_umax[2], s_umax[3]));

    // Bitwise binary search for t = ordered-uint of the k-th largest:
    // t = max value such that count(u >= t) >= k.
    const int kk = *kptr;
    unsigned int t;
    unsigned int xorv = umin ^ umax;
    if (xorv == 0u) {
        t = umax;  // all equal
    } else {
        int hb = 31 - __builtin_clz(xorv);
        unsigned int lowmask = (hb == 31) ? 0xFFFFFFFFu : ((1u << (hb + 1)) - 1u);
        t = umax & ~lowmask;  // common prefix
        for (int bit = hb; bit >= 0; --bit) {
            unsigned int cand = t | (1u << bit);
            int c = 0;
            #pragma unroll
            for (int j = 0; j < 16; ++j) c += (u[j] >= cand) ? 1 : 0;
            #pragma unroll
            for (int off = 32; off; off >>= 1) c += __shfl_down(c, off, 64);
            __syncthreads();                 // protect s_cnt reuse across iters
            if (lane == 0) s_cnt[wid] = c;
            __syncthreads();
            c = s_cnt[0] + s_cnt[1] + s_cnt[2] + s_cnt[3];
            if (c >= kk) t = cand;
        }
    }

    // invert the order-preserving transform
    float thr = __uint_as_float((t & 0x80000000u) ? (t ^ 0x80000000u) : ~t);

    // emit selected kernel vector
    #pragma unroll
    for (int j = 0; j < 16; ++j) {
        int i = tid + j * 256;
        if (i < D) {
            float v = kern[i];
            sel[i] = (v < thr) ? 0.0f : v;
        }
    }
}

// ---------------------------------------------------------------------------
// Kernel B: out[b,d] = x[b,d] * sel[d], float4-vectorized grid-stride.
// x/out are streamed once (nontemporal); sel is 16 KiB -> L1/L2 resident.
// ---------------------------------------------------------------------------
__global__ void __launch_bounds__(256)
bcast_mul_kernel(const f32x4* __restrict__ x,
                 const f32x4* __restrict__ sel,
                 f32x4* __restrict__ out,
                 int n4, int d4mask) {
    int idx = blockIdx.x * blockDim.x + threadIdx.x;
    int stride = gridDim.x * blockDim.x;
    for (int i = idx; i < n4; i += stride) {
        f32x4 xv = __builtin_nontemporal_load(&x[i]);
        f32x4 sv = sel[i & d4mask];
        f32x4 o = xv * sv;
        __builtin_nontemporal_store(o, &out[i]);
    }
}

extern "C" void kernel_launch(void* const* d_in, const int* in_sizes, int n_in,
                              void* d_out, int out_size, void* d_ws, size_t ws_size,
                              hipStream_t stream) {
    const float* x    = (const float*)d_in[0];
    const float* kern = (const float*)d_in[1];
    const int*   kptr = (const int*)d_in[2];
    float* out = (float*)d_out;
    float* sel = (float*)d_ws;  // D floats = 16 KiB scratch

    const int D = in_sizes[1];

    // Phase 1: exact threshold + selected kernel vector (single block, ~3 us)
    select_threshold_kernel<<<1, 256, 0, stream>>>(kern, kptr, sel, D);

    // Phase 2: streaming broadcast multiply
    const int n4 = out_size / 4;          // out_size = B*D, divisible by 4
    const int d4mask = (D / 4) - 1;       // D is a power of two (4096)
    const int blocks = 2048;              // ~8 blocks/CU, grid-stride
    bcast_mul_kernel<<<blocks, 256, 0, stream>>>(
        (const f32x4*)x, (const f32x4*)sel, (f32x4*)out, n4, d4mask);
}